// Round 3
// baseline (579.163 us; speedup 1.0000x reference)
//
#include <hip/hip_runtime.h>
#include <hip/hip_bf16.h>

// LQLinear: out = x @ quantize(weight, basis)^T + bias
// M=8192 tokens, N=4096 out_features, K=4096 in_features.
// Q_T=1 and new_basis is discarded => the LSQ refit does NOT affect output.

#define M_TOK 8192
#define N_OUT 4096
#define K_IN  4096

typedef __attribute__((ext_vector_type(8))) short short8;     // 8 bf16 (4 VGPRs)
typedef __attribute__((ext_vector_type(16))) float floatx16;  // 32x32 MFMA C/D

typedef __attribute__((address_space(1))) const void gvoid_t;
typedef __attribute__((address_space(3))) void lvoid_t;

// round-to-nearest-even fp32 -> bf16 (bit trick; no NaN in this data)
__device__ __forceinline__ ushort f2bf(float f) {
    unsigned u = __float_as_uint(f);
    u += 0x7fffu + ((u >> 16) & 1u);
    return (ushort)(u >> 16);
}

// ---------------- fused prep: x fp32->bf16  +  weight quantize->bf16 -------
// One launch covering both arrays (first nx4 float4 groups are x, rest are w).
__global__ void prep(const float4* __restrict__ x, const float4* __restrict__ w,
                     const float* __restrict__ basis,
                     ushort4* __restrict__ xb, ushort4* __restrict__ wq,
                     int nx4, int nw4) {
    int i = blockIdx.x * blockDim.x + threadIdx.x;
    if (i < nx4) {
        float4 v = x[i];
        ushort4 o;
        o.x = f2bf(v.x); o.y = f2bf(v.y); o.z = f2bf(v.z); o.w = f2bf(v.w);
        xb[i] = o;
    } else {
        int j = i - nx4;
        if (j < nw4) {
            float b0 = basis[0], b1 = basis[1];
            // levels = encodings({-1,+1}^2) @ [b0,b1], sorted ascending
            float l0 = -b0 - b1, l1 = -b0 + b1, l2 = b0 - b1, l3 = b0 + b1;
            float t;
            if (l0 > l1) { t = l0; l0 = l1; l1 = t; }
            if (l2 > l3) { t = l2; l2 = l3; l3 = t; }
            if (l0 > l2) { t = l0; l0 = l2; l2 = t; }
            if (l1 > l3) { t = l1; l1 = l3; l3 = t; }
            if (l1 > l2) { t = l1; l1 = l2; l2 = t; }
            // midpoint thresholds; searchsorted 'left' => idx = #{thres < w}
            float t0 = 0.5f * (l0 + l1), t1 = 0.5f * (l1 + l2), t2 = 0.5f * (l2 + l3);
            float4 v = w[j];
            ushort4 o;
            float q;
            q = (v.x > t1) ? ((v.x > t2) ? l3 : l2) : ((v.x > t0) ? l1 : l0); o.x = f2bf(q);
            q = (v.y > t1) ? ((v.y > t2) ? l3 : l2) : ((v.y > t0) ? l1 : l0); o.y = f2bf(q);
            q = (v.z > t1) ? ((v.z > t2) ? l3 : l2) : ((v.z > t0) ? l1 : l0); o.z = f2bf(q);
            q = (v.w > t1) ? ((v.w > t2) ? l3 : l2) : ((v.w > t0) ? l1 : l0); o.w = f2bf(q);
            wq[j] = o;
        }
    }
}

// ---------------- GEMM: C[M][N] = A[M][K] * B[N][K]^T + bias ----------------
// 128x128 block tile, BK=64, 4 waves in 2x2, each wave 2x2 tiles of
// 32x32x16 MFMA (half the MFMA instr count of 16x16x32 at same FLOP;
// m119: 32x32 ceiling 2495 TF vs 16x16 2075 TF). global_load_lds width=16
// staging with XOR chunk swizzle (conflict-free, verified 0 conflicts R2).
__global__ __launch_bounds__(256) void gemm_bt(
        const ushort* __restrict__ A,   // bf16 [M][K]
        const ushort* __restrict__ B,   // bf16 [N][K]
        const float* __restrict__ bias, // [N]
        float* __restrict__ C) {        // fp32 [M][N]
    __shared__ ushort As[128 * 64];
    __shared__ ushort Bs[128 * 64];

    const int lane = threadIdx.x & 63;
    const int wv   = threadIdx.x >> 6;      // 0..3
    const int bm0  = blockIdx.y * 128;
    const int bn0  = blockIdx.x * 128;
    const int wm   = (wv >> 1) * 64;        // wave row offset in block tile
    const int wn   = (wv & 1) * 64;         // wave col offset

    floatx16 acc[2][2] = {};

    // staging: per wave 4 instrs for A, 4 for B; each instr = 8 rows x 64 cols
    const int lr = lane >> 3;               // 0..7  (row within 8-row group)
    const int lc = lane & 7;                // 0..7  (16B chunk within row)
    // XOR swizzle: LDS slot (row lr, chunk lc) receives global chunk (lc^lr).
    const ushort* ag = A + (size_t)(bm0 + wv * 32 + lr) * K_IN + (lc ^ lr) * 8;
    const ushort* bg = B + (size_t)(bn0 + wv * 32 + lr) * K_IN + (lc ^ lr) * 8;
    ushort* asl = As + (wv * 32) * 64;      // wave-uniform LDS base
    ushort* bsl = Bs + (wv * 32) * 64;

    // MFMA 32x32x16 operand addressing: lane holds row lane&31,
    // k = (lane>>5)*8 + j. Within a 64-elem LDS row, ks-step s needs
    // logical 16B chunk (2s + h), physically at ((2s+h) ^ (row&7)).
    const int m32 = lane & 31;
    const int h   = lane >> 5;              // 0..1

    for (int kt = 0; kt < K_IN / 64; ++kt) {
#pragma unroll
        for (int t = 0; t < 4; ++t) {
            __builtin_amdgcn_global_load_lds((gvoid_t*)(ag + (size_t)t * 8 * K_IN),
                                             (lvoid_t*)(asl + t * 8 * 64), 16, 0, 0);
            __builtin_amdgcn_global_load_lds((gvoid_t*)(bg + (size_t)t * 8 * K_IN),
                                             (lvoid_t*)(bsl + t * 8 * 64), 16, 0, 0);
        }
        ag += 64; bg += 64;
        __syncthreads();
#pragma unroll
        for (int ks = 0; ks < 4; ++ks) {
            const int chunk = ((2 * ks + h) ^ (m32 & 7)) * 8;
            short8 af[2], bfv[2];
#pragma unroll
            for (int i = 0; i < 2; ++i)
                af[i] = *(const short8*)(As + (wm + i * 32 + m32) * 64 + chunk);
#pragma unroll
            for (int j = 0; j < 2; ++j)
                bfv[j] = *(const short8*)(Bs + (wn + j * 32 + m32) * 64 + chunk);
#pragma unroll
            for (int i = 0; i < 2; ++i)
#pragma unroll
                for (int j = 0; j < 2; ++j)
                    acc[i][j] = __builtin_amdgcn_mfma_f32_32x32x16_bf16(
                        af[i], bfv[j], acc[i][j], 0, 0, 0);
        }
        __syncthreads();
    }

    // epilogue: C/D layout col=lane&31, row=(reg&3)+8*(reg>>2)+4*(lane>>5)
    const int c32   = lane & 31;
    const int rbase = h * 4;
#pragma unroll
    for (int j = 0; j < 2; ++j) {
        const int col = bn0 + wn + j * 32 + c32;
        const float bj = bias[col];
#pragma unroll
        for (int i = 0; i < 2; ++i) {
#pragma unroll
            for (int reg = 0; reg < 16; ++reg) {
                const int row = bm0 + wm + i * 32 + rbase + (reg & 3) + 8 * (reg >> 2);
                C[(size_t)row * N_OUT + col] = acc[i][j][reg] + bj;
            }
        }
    }
}

extern "C" void kernel_launch(void* const* d_in, const int* in_sizes, int n_in,
                              void* d_out, int out_size, void* d_ws, size_t ws_size,
                              hipStream_t stream) {
    const float* x     = (const float*)d_in[0];  // [8192,4096]
    const float* w     = (const float*)d_in[1];  // [4096,4096]
    const float* bias  = (const float*)d_in[2];  // [4096]
    const float* basis = (const float*)d_in[3];  // [2]
    float* out = (float*)d_out;                  // [8192,4096] fp32

    ushort* Xb = (ushort*)d_ws;                      // 8192*4096 bf16 = 67.1 MB
    ushort* Wq = Xb + (size_t)M_TOK * K_IN;          // 4096*4096 bf16 = 33.5 MB

    {
        int nx4 = (M_TOK * K_IN) / 4;                // 8388608 (multiple of 256)
        int nw4 = (N_OUT * K_IN) / 4;                // 4194304
        int nblk = (nx4 + nw4) / 256;                // 49152
        prep<<<nblk, 256, 0, stream>>>((const float4*)x, (const float4*)w, basis,
                                       (ushort4*)Xb, (ushort4*)Wq, nx4, nw4);
    }
    {
        dim3 grid(N_OUT / 128, M_TOK / 128);         // (32, 64)
        gemm_bt<<<grid, 256, 0, stream>>>(Xb, Wq, bias, out);
    }
}